// Round 6
// baseline (237.250 us; speedup 1.0000x reference)
//
#include <hip/hip_runtime.h>

// MakeCutouts: 32 cutouts of (8,3,512,512) fp32 -> adaptive avg pool 224x224.
//
// R9: R8's pipeline regressed because it crushed occupancy (768 blocks ->
// 3/CU = 12 waves, 64+ VGPR prefetch state). Deconfound: same counted-wait
// double-buffered band pipeline, but block = (plane, cutout, quarter) with
// 14 bands of TP=4 rows. Tile 2x(4*512+8)*4B = 16.4 KB -> 8 blocks/CU = 32
// waves (same occupancy as the 62us R6/R7 point); prefetch v[2][4] = 32
// VGPR, __launch_bounds__(256,8) pins allocation. Steady state per band:
//   stage_write(band k+1 from regs) | stage_issue(band k+2) | pool(band k)
//   -> barrier waiting ONLY lgkmcnt(0)
// so prefetched global loads stay in flight across the barrier (their wait
// is the data-dependent vmcnt inside the next stage_write). Pool q-params
// amortize over 14 bands. Output stores are nontemporal so the 154 MB write
// stream doesn't evict the XCD-resident source plane from L2. XCD chunk
// swizzle unchanged: 3072 = 8*384, XCD k owns planes [3k,3k+3).

typedef float f32x4 __attribute__((ext_vector_type(4)));

constexpr int OUTSZ = 224;
constexpr int BB    = 8;
constexpr int CC    = 3;
constexpr int HH    = 512;
constexpr int WW    = 512;
constexpr int CUTN  = 32;

constexpr int TP     = 4;              // output rows per band
constexpr int BPB    = 14;             // bands per block (56 total / 4 chunks)
constexpr int NCHUNK = 4;
constexpr int TILEF  = TP * WW + 8;    // 2056 floats per buffer
constexpr int NPLANE = BB * CC;                       // 24
constexpr int NBLOCKS = NPLANE * CUTN * NCHUNK;       // 3072 = 8 * 384
constexpr int NXCD   = 8;
constexpr int CHUNKSZ = NBLOCKS / NXCD;               // 384 = 3 planes worth

// Issue global loads for one band into named regs. wv is readfirstlane'd:
// rs/wp/row-base on SALU, conditional loads under uniform s_cbranch.
// Unloaded v[j][m] are stale but never consumed (same wp at write time).
__device__ __forceinline__ void stage_issue(const float* __restrict__ plane_p,
                                            int S, int p0, int wv, int vo,
                                            f32x4 (&v)[2][4])
{
#pragma unroll
    for (int j = 0; j < 2; ++j) {
        int k  = (wv >> 1) + 2 * j;                        // scalar 0..3
        int p  = p0 + k;
        int rs = (p * S) / OUTSZ;                          // scalar magic div
        int wp = ((p + 1) * S + OUTSZ - 1) / OUTSZ - rs;   // 1..4, scalar
        const f32x4* rp = (const f32x4*)(plane_p + (size_t)rs * WW);
        v[j][0] = rp[vo];
        if (wp > 1) v[j][1] = rp[vo + 128];
        if (wp > 2) v[j][2] = rp[vo + 256];
        if (wp > 3) v[j][3] = rp[vo + 384];
    }
}

// Reduce prefetched rows (v_pk_add_f32 pairs), scale by 1/wp, write one
// 512-wide averaged row per output row into the tile buffer.
__device__ __forceinline__ void stage_write(float* __restrict__ buf,
                                            int S, int p0, int wv, int vo,
                                            f32x4 (&v)[2][4])
{
    f32x4* t4 = (f32x4*)buf;
#pragma unroll
    for (int j = 0; j < 2; ++j) {
        int k  = (wv >> 1) + 2 * j;
        int p  = p0 + k;
        int rs = (p * S) / OUTSZ;
        int wp = ((p + 1) * S + OUTSZ - 1) / OUTSZ - rs;   // 1..4, scalar
        f32x4 a = v[j][0];
        if (wp > 1) a += v[j][1];
        if (wp > 2) a += v[j][2];
        if (wp > 3) a += v[j][3];
        float iv = (wp == 1) ? 1.0f : (wp == 2) ? 0.5f
                 : (wp == 3) ? (1.0f / 3.0f) : 0.25f;      // scalar cselect
        a *= iv;
        t4[k * 128 + vo] = a;             // adjacent lanes -> ds_write_b128
    }
}

// Pool TP rows of one band for this thread's fixed column: 3/4-term fma dot
// with weights {invq or 0}. Weight-0 reads hit finite staged data or the
// zeroed pad, so fma-with-0 is exact. Stores nontemporal (write-once stream).
template <int WIN>
__device__ __forceinline__ void pool_band(const float* __restrict__ buf,
                                          float* __restrict__ outp,
                                          int base, const float* __restrict__ w)
{
#pragma unroll
    for (int k = 0; k < TP; ++k) {
        const float* tr = buf + k * WW + base;
        float s = tr[0] * w[0];           // adjacent cols -> ds_read2_b32
        s = fmaf(tr[1], w[1], s);
        s = fmaf(tr[2], w[2], s);
        if (WIN == 4) s = fmaf(tr[3], w[3], s);
        __builtin_nontemporal_store(s, &outp[(size_t)k * OUTSZ]);
    }
}

// lgkmcnt(0)-only barrier: LDS writes/reads visible; prefetched global loads
// stay in flight (__syncthreads would drain vmcnt(0)).
__device__ __forceinline__ void band_barrier()
{
    asm volatile("s_waitcnt lgkmcnt(0)" ::: "memory");
    __builtin_amdgcn_s_barrier();
}

template <int WIN>
__device__ __forceinline__ void run_bands(const float* __restrict__ plane_p,
                                          float (*tile)[TILEF],
                                          float* __restrict__ outp,
                                          int S, int pbase, int wv, int vo,
                                          int tid, int base,
                                          const float* __restrict__ wt,
                                          f32x4 (&v)[2][4])
{
    for (int k = 0; k < BPB; ++k) {
        if (k + 1 < BPB)                           // consume regs (band k+1)
            stage_write(tile[(k + 1) & 1], S, pbase + (k + 1) * TP, wv, vo, v);
        if (k + 2 < BPB)                           // refill regs (band k+2)
            stage_issue(plane_p, S, pbase + (k + 2) * TP, wv, vo, v);
        if (tid < OUTSZ)                           // pool band k
            pool_band<WIN>(tile[k & 1], outp + (size_t)k * TP * OUTSZ, base, wt);
        band_barrier();
    }
}

__global__ __launch_bounds__(256, 8) void make_cutouts_kernel(
    const float* __restrict__ x,
    const int*   __restrict__ sizes,
    const int*   __restrict__ offy,
    const int*   __restrict__ offx,
    float*       __restrict__ out)
{
    __shared__ float tile[2][TILEF];   // 16448 B -> 8 blocks/CU

    // Bijective XCD chunk swizzle (3072 = 8*384): XCD k owns planes [3k,3k+3).
    int gid = blockIdx.x;
    int w   = (gid % NXCD) * CHUNKSZ + gid / NXCD;
    int plane = w / (CUTN * NCHUNK);        // 0..23 (= b*CC + c)
    int rest  = w - plane * (CUTN * NCHUNK);
    int i     = rest / NCHUNK;              // cutout 0..31
    int ch    = rest - i * NCHUNK;          // quarter 0..3
    int b     = plane / CC;
    int c     = plane - b * CC;

    // block-uniform per-cutout params -> scalar broadcast
    int S  = sizes[i];
    int y0 = offy[i];
    int x0 = offx[i];
    int tid = threadIdx.x;
    int pbase = ch * (BPB * TP);            // 0,56,112,168

    const float* plane_p = x + (size_t)(plane * HH + y0) * WW;

    // zero pads once; stage writes exactly [0,2048) so they stay zero.
    if (tid < 8) {
        tile[0][TP * WW + tid] = 0.0f;
        tile[1][TP * WW + tid] = 0.0f;
    }

    int wv   = __builtin_amdgcn_readfirstlane(tid >> 6);  // 0..3
    int lane = tid & 63;
    int vo   = ((wv & 1) << 6) + lane;      // float4 col index 0..127

    // pool params: once per block, reused for 14 bands.
    int sq = (tid * S) / OUTSZ;
    int wq = ((tid + 1) * S + OUTSZ - 1) / OUTSZ - sq;     // 1..4
    float invq = (wq == 1) ? 1.0f : (wq == 2) ? 0.5f
               : (wq == 3) ? (1.0f / 3.0f) : 0.25f;
    float wt[4];
    wt[0] = invq;
    wt[1] = (wq > 1) ? invq : 0.0f;
    wt[2] = (wq > 2) ? invq : 0.0f;
    wt[3] = (wq > 3) ? invq : 0.0f;
    int base = x0 + sq;
    float* outp = out
        + ((size_t)((i * BB + b) * CC + c) * OUTSZ + pbase) * OUTSZ + tid;

    // prologue: band 0 staged synchronously; band 1 loads issued.
    f32x4 v[2][4];
    stage_issue(plane_p, S, pbase, wv, vo, v);
    stage_write(tile[0], S, pbase, wv, vo, v);
    stage_issue(plane_p, S, pbase + TP, wv, vo, v);
    band_barrier();

    if (S <= 2 * OUTSZ)   // block-uniform: max bin width 3
        run_bands<3>(plane_p, tile, outp, S, pbase, wv, vo, tid, base, wt, v);
    else                  // S in (448,512]: max bin width 4
        run_bands<4>(plane_p, tile, outp, S, pbase, wv, vo, tid, base, wt, v);
}

extern "C" void kernel_launch(void* const* d_in, const int* in_sizes, int n_in,
                              void* d_out, int out_size, void* d_ws, size_t ws_size,
                              hipStream_t stream) {
    const float* x     = (const float*)d_in[0];
    const int*   sizes = (const int*)d_in[1];
    const int*   offy  = (const int*)d_in[2];
    const int*   offx  = (const int*)d_in[3];
    float* out = (float*)d_out;

    make_cutouts_kernel<<<NBLOCKS, 256, 0, stream>>>(x, sizes, offy, offx, out);
}